// Round 2
// baseline (182.387 us; speedup 1.0000x reference)
//
#include <hip/hip_runtime.h>

#define SRC_LEN 256
#define TRG_LEN 256
#define BATCH   32
#define HID     512
#define ATT     128
#define CSCALE  2.885390081777927f   // 2*log2(e): exp2(CSCALE*x) == exp(2x)
#define RSTR    68                   // padded LDS stride (floats) for row tile

// ---------------------------------------------------------------------------
// Fused projection kernel.
//  blocks [0,256):   encT[b][a][s] = CSCALE * sum_k enc_outs[s][b][k]*W_s[a][k]
//  blocks [256,512): decC[t][b][a] = CSCALE * (sum_k dec_out[t][b][k]*W_t[a][k] + b_t[a])
// Tile: 32 rows x 128 cols, K-chunk 64, 256 threads, thread-tile 4x4.
// R1: k-block-4 inner loop (ds_read_b128 for row tile) + register
// double-buffer prefetch of the next global chunk to hide HBM latency
// (only 2 blocks/CU resident -> latency hiding must come from ILP).
// ---------------------------------------------------------------------------
__global__ __launch_bounds__(256) void proj_kernel(
    const float* __restrict__ dec_out, const float* __restrict__ enc_outs,
    const float* __restrict__ W_s, const float* __restrict__ W_t,
    const float* __restrict__ b_t,
    float* __restrict__ encT, float* __restrict__ decC)
{
    __shared__ float rowsL[32 * RSTR];
    __shared__ float wL[64 * 128];

    const int blk   = blockIdx.x;
    const bool isDec = (blk >= 256);
    const int r0    = (isDec ? blk - 256 : blk) * 32;   // row = (s or t)*32 + b
    const float* __restrict__ in = isDec ? dec_out : enc_outs;
    const float* __restrict__ W  = isDec ? W_t : W_s;

    const int tid = threadIdx.x;
    const int ct  = tid & 31;   // col group: a = ct*4 .. ct*4+3
    const int rt  = tid >> 5;   // row group: local rows rt*4 .. rt*4+3

    // staging-index precompute (same every chunk)
    const int ri = tid >> 4, rkc = tid & 15;          // row-tile: 2 iters
    const int wa0 = tid >> 4;                          // w-tile: 8 iters, a = wa0 + it*16... no:
    // w-tile: f = tid + it*256; a = f>>4 = (tid>>4) + it*16, kc = tid&15

    float acc[4][4];
    #pragma unroll
    for (int i = 0; i < 4; ++i)
        #pragma unroll
        for (int j = 0; j < 4; ++j) acc[i][j] = 0.0f;

    float4 rbuf[2];
    float4 wbuf[8];

    // prefetch chunk 0
    #pragma unroll
    for (int it = 0; it < 2; ++it)
        rbuf[it] = *(const float4*)(in + (size_t)(r0 + ri + it * 16) * HID + rkc * 4);
    #pragma unroll
    for (int it = 0; it < 8; ++it)
        wbuf[it] = *(const float4*)(W + (size_t)(wa0 + it * 16) * HID + rkc * 4);

    for (int c = 0; c < 8; ++c) {
        __syncthreads();   // previous compute done reading LDS
        // store staged regs -> LDS
        #pragma unroll
        for (int it = 0; it < 2; ++it)
            *(float4*)(rowsL + (ri + it * 16) * RSTR + rkc * 4) = rbuf[it];
        #pragma unroll
        for (int it = 0; it < 8; ++it) {
            const int a = wa0 + it * 16;
            const int sw = a ^ (4 * (rkc & 7));
            const float4 v = wbuf[it];
            wL[(rkc * 4 + 0) * 128 + sw] = v.x;
            wL[(rkc * 4 + 1) * 128 + sw] = v.y;
            wL[(rkc * 4 + 2) * 128 + sw] = v.z;
            wL[(rkc * 4 + 3) * 128 + sw] = v.w;
        }
        __syncthreads();

        // prefetch next chunk while computing this one
        if (c < 7) {
            const int k0 = (c + 1) * 64;
            #pragma unroll
            for (int it = 0; it < 2; ++it)
                rbuf[it] = *(const float4*)(in + (size_t)(r0 + ri + it * 16) * HID + k0 + rkc * 4);
            #pragma unroll
            for (int it = 0; it < 8; ++it)
                wbuf[it] = *(const float4*)(W + (size_t)(wa0 + it * 16) * HID + k0 + rkc * 4);
        }

        #pragma unroll
        for (int kb = 0; kb < 64; kb += 4) {
            const int sw = (ct * 4) ^ (4 * ((kb >> 2) & 7));   // constant over kb..kb+3
            float4 w0 = *(const float4*)(wL + (kb + 0) * 128 + sw);
            float4 w1 = *(const float4*)(wL + (kb + 1) * 128 + sw);
            float4 w2 = *(const float4*)(wL + (kb + 2) * 128 + sw);
            float4 w3 = *(const float4*)(wL + (kb + 3) * 128 + sw);
            float4 e0 = *(const float4*)(rowsL + (rt * 4 + 0) * RSTR + kb);
            float4 e1 = *(const float4*)(rowsL + (rt * 4 + 1) * RSTR + kb);
            float4 e2 = *(const float4*)(rowsL + (rt * 4 + 2) * RSTR + kb);
            float4 e3 = *(const float4*)(rowsL + (rt * 4 + 3) * RSTR + kb);

            #define FMA4(i, ev)                                   \
                acc[i][0] = fmaf(ev.x, w0.x, acc[i][0]);          \
                acc[i][1] = fmaf(ev.x, w0.y, acc[i][1]);          \
                acc[i][2] = fmaf(ev.x, w0.z, acc[i][2]);          \
                acc[i][3] = fmaf(ev.x, w0.w, acc[i][3]);          \
                acc[i][0] = fmaf(ev.y, w1.x, acc[i][0]);          \
                acc[i][1] = fmaf(ev.y, w1.y, acc[i][1]);          \
                acc[i][2] = fmaf(ev.y, w1.z, acc[i][2]);          \
                acc[i][3] = fmaf(ev.y, w1.w, acc[i][3]);          \
                acc[i][0] = fmaf(ev.z, w2.x, acc[i][0]);          \
                acc[i][1] = fmaf(ev.z, w2.y, acc[i][1]);          \
                acc[i][2] = fmaf(ev.z, w2.z, acc[i][2]);          \
                acc[i][3] = fmaf(ev.z, w2.w, acc[i][3]);          \
                acc[i][0] = fmaf(ev.w, w3.x, acc[i][0]);          \
                acc[i][1] = fmaf(ev.w, w3.y, acc[i][1]);          \
                acc[i][2] = fmaf(ev.w, w3.z, acc[i][2]);          \
                acc[i][3] = fmaf(ev.w, w3.w, acc[i][3]);
            FMA4(0, e0)
            FMA4(1, e1)
            FMA4(2, e2)
            FMA4(3, e3)
            #undef FMA4
        }
    }

    if (!isDec) {
        const int s = blk;   // rows r0..r0+31 are s = blk, b = 0..31
        #pragma unroll
        for (int rr = 0; rr < 4; ++rr) {
            const int b = rt * 4 + rr;
            #pragma unroll
            for (int cc = 0; cc < 4; ++cc) {
                const int a = ct * 4 + cc;
                encT[((size_t)b * ATT + a) * SRC_LEN + s] = acc[rr][cc] * CSCALE;
            }
        }
    } else {
        #pragma unroll
        for (int rr = 0; rr < 4; ++rr) {
            const int r = r0 + rt * 4 + rr;
            float4 o;
            o.x = (acc[rr][0] + b_t[ct * 4 + 0]) * CSCALE;
            o.y = (acc[rr][1] + b_t[ct * 4 + 1]) * CSCALE;
            o.z = (acc[rr][2] + b_t[ct * 4 + 2]) * CSCALE;
            o.w = (acc[rr][3] + b_t[ct * 4 + 3]) * CSCALE;
            *(float4*)(decC + (size_t)r * ATT + ct * 4) = o;
        }
    }
}

// ---------------------------------------------------------------------------
// Score kernel: scores[t][b][s] = sum_a v[a]*tanh(enc_att[s][b][a]+dec_att[t][b][a])
// With eS = CSCALE*enc_att, dS = CSCALE*dec_att (pre-scaled in proj):
//   tanh = 1 - 2/(1+exp2(eS+dS));  score = sumV - 2 * sum_a v[a]/(1+exp2(m))
// R1: t-tile 8 -> 4. Grid (64,32)=2048 blocks = 8192 waves = 100% of the
// 256CU x 32wave slots (was 29% occupancy, latency-bound on exp/rcp chains).
// ---------------------------------------------------------------------------
__global__ __launch_bounds__(256) void score_kernel(
    const float* __restrict__ encT, const float* __restrict__ decC,
    const float* __restrict__ v_a, float* __restrict__ out)
{
    __shared__ float dS[4 * ATT];
    __shared__ float vS[ATT];
    __shared__ float sumvS;

    const int tid = threadIdx.x;
    const int t0  = blockIdx.x * 4;
    const int b   = blockIdx.y;

    // stage dec tile (4 x 128) and v
    if (tid < 128) {
        const int tt = tid >> 5, a4 = (tid & 31) * 4;
        float4 v = *(const float4*)(decC + ((size_t)(t0 + tt) * BATCH + b) * ATT + a4);
        *(float4*)(dS + tt * ATT + a4) = v;
    } else if (tid < 160) {
        const int l = tid - 128;
        float4 v = *(const float4*)(v_a + l * 4);
        *(float4*)(vS + l * 4) = v;
    }
    __syncthreads();
    if (tid < 64) {
        float x = vS[tid] + vS[tid + 64];
        #pragma unroll
        for (int o = 32; o > 0; o >>= 1) x += __shfl_down(x, o);
        if (tid == 0) sumvS = x;
    }
    __syncthreads();

    float acc[4];
    #pragma unroll
    for (int tt = 0; tt < 4; ++tt) acc[tt] = 0.0f;

    const float* __restrict__ ep = encT + (size_t)b * ATT * SRC_LEN + tid;

    #pragma unroll 4
    for (int a = 0; a < ATT; ++a) {
        const float e  = ep[a * SRC_LEN];     // coalesced: lane = s
        const float va = vS[a];
        #pragma unroll
        for (int tt = 0; tt < 4; ++tt) {
            const float m = e + dS[tt * ATT + a];
            const float p = __builtin_amdgcn_exp2f(m);
            const float r = __builtin_amdgcn_rcpf(1.0f + p);
            acc[tt] = fmaf(va, r, acc[tt]);
        }
    }

    const float sv = sumvS;
    #pragma unroll
    for (int tt = 0; tt < 4; ++tt) {
        out[((size_t)(t0 + tt) * BATCH + b) * SRC_LEN + tid] = sv - 2.0f * acc[tt];
    }
}

extern "C" void kernel_launch(void* const* d_in, const int* in_sizes, int n_in,
                              void* d_out, int out_size, void* d_ws, size_t ws_size,
                              hipStream_t stream) {
    const float* dec_out  = (const float*)d_in[0];
    const float* enc_outs = (const float*)d_in[1];
    const float* W_s      = (const float*)d_in[2];
    const float* W_t      = (const float*)d_in[3];
    const float* b_t      = (const float*)d_in[4];
    const float* v_a      = (const float*)d_in[5];
    float* out = (float*)d_out;

    float* encT = (float*)d_ws;                              // B*A*S  = 4 MB
    float* decC = encT + (size_t)BATCH * ATT * SRC_LEN;      // T*B*A  = 4 MB

    proj_kernel<<<512, 256, 0, stream>>>(dec_out, enc_outs, W_s, W_t, b_t, encT, decC);

    dim3 g3(TRG_LEN / 4, BATCH);
    score_kernel<<<g3, 256, 0, stream>>>(encT, decC, v_a, out);
}

// Round 3
// 128.200 us; speedup vs baseline: 1.4227x; 1.4227x over previous
//
#include <hip/hip_runtime.h>

#define SRC_LEN 256
#define TRG_LEN 256
#define BATCH   32
#define HID     512
#define ATT     128
#define CSCALE  2.885390081777927f   // 2*log2(e): exp2(CSCALE*x) == exp(2x)

typedef float  f32x4  __attribute__((ext_vector_type(4)));
typedef short  bf16x8 __attribute__((ext_vector_type(8)));

// manual RNE fp32->bf16 (inputs are finite normals; NaN path not needed)
__device__ inline unsigned short bfr(float x) {
    unsigned u = __builtin_bit_cast(unsigned, x);
    return (unsigned short)((u + 0x7fffu + ((u >> 16) & 1u)) >> 16);
}
__device__ inline unsigned pkbf(float a, float b) {
    return (unsigned)bfr(a) | ((unsigned)bfr(b) << 16);
}

// ---------------------------------------------------------------------------
// MFMA projection. M = 16384 rows (128 enc-blocks: fixed b, 64 s; 128 dec-
// blocks: fixed b, 64 t), N = 128 (a), K = 512. Block tile 64x128, 4 waves
// each 32m x 64n = 2x4 mfma_f32_16x16x32_bf16. fp32->bf16 in staging.
// LDS: XOR-swizzled 16B k-groups -> conflict-free ds_read_b128 fragments.
// Epilogues: enc stores E' = exp(-2*enc_att) transposed [b][a][s] via padded
// LDS transpose; dec stores D = exp(+2*(dec_att+b_t)) as [t][b][a] direct.
// ---------------------------------------------------------------------------
__global__ __launch_bounds__(256) void proj_mfma(
    const float* __restrict__ dec_out, const float* __restrict__ enc_outs,
    const float* __restrict__ W_s, const float* __restrict__ W_t,
    const float* __restrict__ b_t,
    float* __restrict__ encE, float* __restrict__ decD)
{
    __shared__ __align__(16) char smem[49152];
    char* aLb = smem;            // [2][64 rows][64 k] bf16 = 2 x 8192 B
    char* bLb = smem + 16384;    // [2][128 rows][64 k] bf16 = 2 x 16384 B

    const int tid   = threadIdx.x;
    const int blk   = blockIdx.x;
    const bool isDec = blk >= 128;
    const int bb    = blk & 31;
    const int r0    = ((isDec ? blk - 128 : blk) >> 5) * 64;  // s0 or t0
    const float* __restrict__ in = isDec ? dec_out : enc_outs;
    const float* __restrict__ W  = isDec ? W_t : W_s;

    const int lane   = tid & 63;
    const int w      = tid >> 6;
    const int woff_m = (w >> 1) * 32;
    const int woff_n = (w & 1) * 64;
    const int q      = lane >> 4;
    const int l15    = lane & 15;
    const int l7     = lane & 7;

    // staging thread mapping
    const int am  = tid >> 2, akq = tid & 3;   // A: row am (0..63), 16-k seg
    const int wn  = tid >> 1, wkh = tid & 1;   // W: row wn (0..127), 32-k half
    const float* aGp = in + ((size_t)(r0 + am) * BATCH + bb) * HID + akq * 16;
    const float* wGp = W + (size_t)wn * HID + wkh * 32;

    float4 aR[4];
    float4 wR[8];

    f32x4 acc[2][4];
    #pragma unroll
    for (int mi = 0; mi < 2; ++mi)
        #pragma unroll
        for (int ni = 0; ni < 4; ++ni) acc[mi][ni] = (f32x4)0.0f;

    #define LOADG(c)                                                     \
        {                                                                \
            _Pragma("unroll")                                            \
            for (int i = 0; i < 4; ++i)                                  \
                aR[i] = *(const float4*)(aGp + (c) * 64 + i * 4);        \
            _Pragma("unroll")                                            \
            for (int i = 0; i < 8; ++i)                                  \
                wR[i] = *(const float4*)(wGp + (c) * 64 + i * 4);        \
        }

    #define STORES(buf)                                                  \
        {                                                                \
            char* ab = aLb + (buf) * 8192;                               \
            _Pragma("unroll")                                            \
            for (int h = 0; h < 2; ++h) {                                \
                uint4 pk;                                                \
                float4 f0 = aR[2 * h], f1 = aR[2 * h + 1];               \
                pk.x = pkbf(f0.x, f0.y); pk.y = pkbf(f0.z, f0.w);        \
                pk.z = pkbf(f1.x, f1.y); pk.w = pkbf(f1.z, f1.w);        \
                int g = akq * 2 + h;                                     \
                *(uint4*)(ab + am * 128 + ((g ^ (am & 7)) * 16)) = pk;   \
            }                                                            \
            char* bp = bLb + (buf) * 16384;                              \
            _Pragma("unroll")                                            \
            for (int h = 0; h < 4; ++h) {                                \
                uint4 pk;                                                \
                float4 f0 = wR[2 * h], f1 = wR[2 * h + 1];               \
                pk.x = pkbf(f0.x, f0.y); pk.y = pkbf(f0.z, f0.w);        \
                pk.z = pkbf(f1.x, f1.y); pk.w = pkbf(f1.z, f1.w);        \
                int g = wkh * 4 + h;                                     \
                *(uint4*)(bp + wn * 128 + ((g ^ (wn & 7)) * 16)) = pk;   \
            }                                                            \
        }

    LOADG(0);
    STORES(0);
    __syncthreads();

    for (int c = 0; c < 8; ++c) {
        if (c < 7) LOADG(c + 1);
        const char* ab = aLb + (c & 1) * 8192;
        const char* bp = bLb + (c & 1) * 16384;
        #pragma unroll
        for (int s = 0; s < 2; ++s) {
            bf16x8 af[2], bfv[4];
            const int sw = ((s * 4 + q) ^ l7) * 16;
            #pragma unroll
            for (int mi = 0; mi < 2; ++mi)
                af[mi] = *(const bf16x8*)(ab + (woff_m + mi * 16 + l15) * 128 + sw);
            #pragma unroll
            for (int ni = 0; ni < 4; ++ni)
                bfv[ni] = *(const bf16x8*)(bp + (woff_n + ni * 16 + l15) * 128 + sw);
            #pragma unroll
            for (int mi = 0; mi < 2; ++mi)
                #pragma unroll
                for (int ni = 0; ni < 4; ++ni)
                    acc[mi][ni] = __builtin_amdgcn_mfma_f32_16x16x32_bf16(
                        af[mi], bfv[ni], acc[mi][ni], 0, 0, 0);
        }
        if (c < 7) STORES((c + 1) & 1);
        __syncthreads();
    }

    if (!isDec) {
        // E' = exp(-2*enc_att), transposed store via padded LDS (stride 129)
        float* T = (float*)smem;
        #pragma unroll
        for (int mi = 0; mi < 2; ++mi)
            #pragma unroll
            for (int ni = 0; ni < 4; ++ni)
                #pragma unroll
                for (int r = 0; r < 4; ++r) {
                    const int ml = woff_m + mi * 16 + q * 4 + r;
                    const int nl = woff_n + ni * 16 + l15;
                    T[ml * 129 + nl] = __builtin_amdgcn_exp2f(-CSCALE * acc[mi][ni][r]);
                }
        __syncthreads();
        const int m  = tid & 63;
        const int n0 = tid >> 6;
        #pragma unroll
        for (int p = 0; p < 32; ++p) {
            const int n = n0 + p * 4;
            encE[((size_t)(bb * ATT + n)) * SRC_LEN + r0 + m] = T[m * 129 + n];
        }
    } else {
        // D = exp(+2*(dec_att + b_t)), natural [t][b][a] store
        float bt[4];
        #pragma unroll
        for (int ni = 0; ni < 4; ++ni) bt[ni] = b_t[woff_n + ni * 16 + l15];
        #pragma unroll
        for (int mi = 0; mi < 2; ++mi)
            #pragma unroll
            for (int ni = 0; ni < 4; ++ni)
                #pragma unroll
                for (int r = 0; r < 4; ++r) {
                    const int ml = woff_m + mi * 16 + q * 4 + r;
                    const int nl = woff_n + ni * 16 + l15;
                    decD[((size_t)(r0 + ml) * BATCH + bb) * ATT + nl] =
                        __builtin_amdgcn_exp2f(CSCALE * (acc[mi][ni][r] + bt[ni]));
                }
    }
    #undef LOADG
    #undef STORES
}

// ---------------------------------------------------------------------------
// Score: v.tanh(e+d) = v - 2*v*E'/(E'+D), E'=exp(-2e) per-lane (lane=s),
// D=exp(2d) wave-broadcast from LDS. Per element: add + rcp + fma
// (1 transcendental instead of 2). LDS broadcasts batched as float4.
// Grid (64,32) = 2048 blocks = 100% wave-slot occupancy.
// ---------------------------------------------------------------------------
__global__ __launch_bounds__(256) void score_kernel(
    const float* __restrict__ encE, const float* __restrict__ decD,
    const float* __restrict__ v_a, float* __restrict__ out)
{
    __shared__ float dS[4 * ATT];
    __shared__ float vS[ATT];
    __shared__ float sumvS;

    const int tid = threadIdx.x;
    const int t0  = blockIdx.x * 4;
    const int b   = blockIdx.y;

    if (tid < 128) {
        const int tt = tid >> 5, a4 = (tid & 31) * 4;
        *(float4*)(dS + tt * ATT + a4) =
            *(const float4*)(decD + ((size_t)(t0 + tt) * BATCH + b) * ATT + a4);
    } else if (tid < 160) {
        const int l = tid - 128;
        *(float4*)(vS + l * 4) = *(const float4*)(v_a + l * 4);
    }
    __syncthreads();
    if (tid < 64) {
        float x = vS[tid] + vS[tid + 64];
        #pragma unroll
        for (int o = 32; o > 0; o >>= 1) x += __shfl_down(x, o);
        if (tid == 0) sumvS = x;
    }
    __syncthreads();

    float acc0 = 0.f, acc1 = 0.f, acc2 = 0.f, acc3 = 0.f;
    const float* __restrict__ ep = encE + (size_t)b * ATT * SRC_LEN + tid;

    #pragma unroll 2
    for (int g = 0; g < 32; ++g) {
        float4 E;
        E.x = ep[(g * 4 + 0) * SRC_LEN];
        E.y = ep[(g * 4 + 1) * SRC_LEN];
        E.z = ep[(g * 4 + 2) * SRC_LEN];
        E.w = ep[(g * 4 + 3) * SRC_LEN];
        const float4 v4 = *(const float4*)(vS + g * 4);
        const float4 d0 = *(const float4*)(dS + 0 * ATT + g * 4);
        const float4 d1 = *(const float4*)(dS + 1 * ATT + g * 4);
        const float4 d2 = *(const float4*)(dS + 2 * ATT + g * 4);
        const float4 d3 = *(const float4*)(dS + 3 * ATT + g * 4);
        float4 vE;
        vE.x = v4.x * E.x; vE.y = v4.y * E.y;
        vE.z = v4.z * E.z; vE.w = v4.w * E.w;

        acc0 = fmaf(vE.x, __builtin_amdgcn_rcpf(E.x + d0.x), acc0);
        acc0 = fmaf(vE.y, __builtin_amdgcn_rcpf(E.y + d0.y), acc0);
        acc0 = fmaf(vE.z, __builtin_amdgcn_rcpf(E.z + d0.z), acc0);
        acc0 = fmaf(vE.w, __builtin_amdgcn_rcpf(E.w + d0.w), acc0);
        acc1 = fmaf(vE.x, __builtin_amdgcn_rcpf(E.x + d1.x), acc1);
        acc1 = fmaf(vE.y, __builtin_amdgcn_rcpf(E.y + d1.y), acc1);
        acc1 = fmaf(vE.z, __builtin_amdgcn_rcpf(E.z + d1.z), acc1);
        acc1 = fmaf(vE.w, __builtin_amdgcn_rcpf(E.w + d1.w), acc1);
        acc2 = fmaf(vE.x, __builtin_amdgcn_rcpf(E.x + d2.x), acc2);
        acc2 = fmaf(vE.y, __builtin_amdgcn_rcpf(E.y + d2.y), acc2);
        acc2 = fmaf(vE.z, __builtin_amdgcn_rcpf(E.z + d2.z), acc2);
        acc2 = fmaf(vE.w, __builtin_amdgcn_rcpf(E.w + d2.w), acc2);
        acc3 = fmaf(vE.x, __builtin_amdgcn_rcpf(E.x + d3.x), acc3);
        acc3 = fmaf(vE.y, __builtin_amdgcn_rcpf(E.y + d3.y), acc3);
        acc3 = fmaf(vE.z, __builtin_amdgcn_rcpf(E.z + d3.z), acc3);
        acc3 = fmaf(vE.w, __builtin_amdgcn_rcpf(E.w + d3.w), acc3);
    }

    const float sv = sumvS;
    out[((size_t)(t0 + 0) * BATCH + b) * SRC_LEN + tid] = sv - 2.0f * acc0;
    out[((size_t)(t0 + 1) * BATCH + b) * SRC_LEN + tid] = sv - 2.0f * acc1;
    out[((size_t)(t0 + 2) * BATCH + b) * SRC_LEN + tid] = sv - 2.0f * acc2;
    out[((size_t)(t0 + 3) * BATCH + b) * SRC_LEN + tid] = sv - 2.0f * acc3;
}

extern "C" void kernel_launch(void* const* d_in, const int* in_sizes, int n_in,
                              void* d_out, int out_size, void* d_ws, size_t ws_size,
                              hipStream_t stream) {
    const float* dec_out  = (const float*)d_in[0];
    const float* enc_outs = (const float*)d_in[1];
    const float* W_s      = (const float*)d_in[2];
    const float* W_t      = (const float*)d_in[3];
    const float* b_t      = (const float*)d_in[4];
    const float* v_a      = (const float*)d_in[5];
    float* out = (float*)d_out;

    float* encE = (float*)d_ws;                              // B*A*S = 4 MB : exp(-2*enc_att)
    float* decD = encE + (size_t)BATCH * ATT * SRC_LEN;      // T*B*A = 4 MB : exp(+2*dec_att)

    proj_mfma<<<256, 256, 0, stream>>>(dec_out, enc_outs, W_s, W_t, b_t, encE, decD);

    dim3 g3(TRG_LEN / 4, BATCH);
    score_kernel<<<g3, 256, 0, stream>>>(encE, decD, v_a, out);
}